// Round 1
// baseline (951.614 us; speedup 1.0000x reference)
//
#include <hip/hip_runtime.h>
#include <hip/hip_bf16.h>

#define NN 10000
#define NE 640000
#define NF 128
#define NH 128
#define NT 128
#define KA 256   // NF + NH
#define LN_EPS 1e-5f

typedef __bf16 bf16x8 __attribute__((ext_vector_type(8)));
typedef float floatx4 __attribute__((ext_vector_type(4)));

__device__ inline unsigned short f2bf(float f) {
    unsigned int u = __float_as_uint(f);
    u += 0x7FFFu + ((u >> 16) & 1u);   // round-to-nearest-even
    return (unsigned short)(u >> 16);
}

__device__ inline bf16x8 load_frag(const unsigned short* p) {
    uint4 u = *(const uint4*)p;
    return __builtin_bit_cast(bf16x8, u);
}

// ---------------------------------------------------------------------------
// Prologue: convert all four weight matrices f32 [K][N] -> bf16 [N][K]
// (transposed so B-fragments are 16B-contiguous per lane).
// ---------------------------------------------------------------------------
__global__ __launch_bounds__(256) void conv_weights(
    const float* __restrict__ W1a, const float* __restrict__ W1b,
    const float* __restrict__ W2a, const float* __restrict__ W2b,
    unsigned short* __restrict__ wt1a, unsigned short* __restrict__ wt1b,
    unsigned short* __restrict__ wt2a, unsigned short* __restrict__ wt2b)
{
    int tid = blockIdx.x * 256 + threadIdx.x;
    if (tid < 32768) {                       // W1a: [256][128] -> [128][256]
        int n = tid >> 8, k = tid & 255;
        wt1a[tid] = f2bf(W1a[k * 128 + n]);
    } else if (tid < 49152) {                // W1b: [128][128]
        int t = tid - 32768;
        int n = t >> 7, k = t & 127;
        wt1b[t] = f2bf(W1b[k * 128 + n]);
    } else if (tid < 81920) {                // W2a: [256][128]
        int t = tid - 49152;
        int n = t >> 8, k = t & 255;
        wt2a[t] = f2bf(W2a[k * 128 + n]);
    } else if (tid < 98304) {                // W2b: [128][128]
        int t = tid - 81920;
        int n = t >> 7, k = t & 127;
        wt2b[t] = f2bf(W2b[k * 128 + n]);
    }
}

__global__ __launch_bounds__(256) void count_edges(
    const int* __restrict__ row, float* __restrict__ cnt)
{
    int e = blockIdx.x * 256 + threadIdx.x;
    if (e < NE) atomicAdd(&cnt[row[e]], 1.0f);
}

// ---------------------------------------------------------------------------
// Edge MLP + scatter-add. One wave = 16 edges. Block = 4 waves = 64 edges.
// ---------------------------------------------------------------------------
__global__ __launch_bounds__(256) void edge_mlp_kernel(
    const float* __restrict__ x,
    const int* __restrict__ erow, const int* __restrict__ ecol,
    const float* __restrict__ eattr,
    const unsigned short* __restrict__ wt1a, const float* __restrict__ b1a,
    const float* __restrict__ g1, const float* __restrict__ be1,
    const unsigned short* __restrict__ wt1b, const float* __restrict__ b1b,
    float* __restrict__ sums)
{
    __shared__ unsigned short Atile[4][16][KA + 8];  // +8 bf16 pad: row stride 528B (16B-aligned, 2-way banks)
    __shared__ unsigned short Ttile[4][16][NH + 8];

    const int wave = threadIdx.x >> 6;
    const int lane = threadIdx.x & 63;
    const int e0 = blockIdx.x * 64 + wave * 16;

    // ---- stage A = [x[col[e]] | edge_attr[e]] as bf16 into LDS ----
    {
        const int lrow = lane >> 2;      // 0..15 edge row
        const int lq   = lane & 3;       // 0..3
        const int e = e0 + lrow;
        const int src = ecol[e];
        const float4* xr = (const float4*)(x + src * NF);
        const float4* ar = (const float4*)(eattr + (size_t)e * NH);
        unsigned short* Ar = &Atile[wave][lrow][0];
#pragma unroll
        for (int it = 0; it < 8; ++it) {
            int c4 = lq + it * 4;        // 0..31 float4 index
            float4 v = xr[c4];
            uint2 w;
            w.x = (unsigned)f2bf(v.x) | ((unsigned)f2bf(v.y) << 16);
            w.y = (unsigned)f2bf(v.z) | ((unsigned)f2bf(v.w) << 16);
            *(uint2*)&Ar[c4 * 4] = w;
            float4 v2 = ar[c4];
            uint2 w2;
            w2.x = (unsigned)f2bf(v2.x) | ((unsigned)f2bf(v2.y) << 16);
            w2.y = (unsigned)f2bf(v2.z) | ((unsigned)f2bf(v2.w) << 16);
            *(uint2*)&Ar[128 + c4 * 4] = w2;
        }
    }
    __syncthreads();

    const int lm  = lane & 15;   // A row / B col / C col
    const int lq4 = lane >> 4;   // quad: k-block for A/B, row-block for C

    // ---- GEMM1: [16 x 256] @ [256 x 128] ----
    bf16x8 a1[8];
#pragma unroll
    for (int ks = 0; ks < 8; ++ks)
        a1[ks] = load_frag(&Atile[wave][lm][ks * 32 + lq4 * 8]);

    floatx4 acc1[8];
#pragma unroll
    for (int ct = 0; ct < 8; ++ct) {
        floatx4 acc = {0.f, 0.f, 0.f, 0.f};
        const unsigned short* wr = wt1a + (ct * 16 + lm) * KA + lq4 * 8;
#pragma unroll
        for (int ks = 0; ks < 8; ++ks) {
            bf16x8 b = load_frag(wr + ks * 32);
            acc = __builtin_amdgcn_mfma_f32_16x16x32_bf16(a1[ks], b, acc, 0, 0, 0);
        }
        acc1[ct] = acc;
    }

    // ---- bias + ReLU + LayerNorm (rows live across 16 lanes sharing lq4) ----
    float sum_[4] = {0, 0, 0, 0}, sq_[4] = {0, 0, 0, 0};
#pragma unroll
    for (int ct = 0; ct < 8; ++ct) {
        const float bb = b1a[ct * 16 + lm];
#pragma unroll
        for (int i = 0; i < 4; ++i) {
            float v = acc1[ct][i] + bb;
            v = fmaxf(v, 0.f);
            acc1[ct][i] = v;
            sum_[i] += v;
            sq_[i]  += v * v;
        }
    }
#pragma unroll
    for (int m = 1; m < 16; m <<= 1) {
#pragma unroll
        for (int i = 0; i < 4; ++i) {
            sum_[i] += __shfl_xor(sum_[i], m, 64);
            sq_[i]  += __shfl_xor(sq_[i],  m, 64);
        }
    }
    float mu[4], rs[4];
#pragma unroll
    for (int i = 0; i < 4; ++i) {
        mu[i] = sum_[i] * (1.f / NH);
        float var = sq_[i] * (1.f / NH) - mu[i] * mu[i];
        rs[i] = rsqrtf(var + LN_EPS);
    }
    // write normalized t to LDS in A-operand layout for GEMM2
#pragma unroll
    for (int ct = 0; ct < 8; ++ct) {
        const int c = ct * 16 + lm;
        const float gg = g1[c], bb = be1[c];
#pragma unroll
        for (int i = 0; i < 4; ++i) {
            float nv = (acc1[ct][i] - mu[i]) * rs[i] * gg + bb;
            Ttile[wave][lq4 * 4 + i][c] = f2bf(nv);
        }
    }
    __syncthreads();

    // ---- GEMM2: [16 x 128] @ [128 x 128] + scatter-add ----
    bf16x8 a2[4];
#pragma unroll
    for (int ks = 0; ks < 4; ++ks)
        a2[ks] = load_frag(&Ttile[wave][lm][ks * 32 + lq4 * 8]);

    int ridx[4];
#pragma unroll
    for (int i = 0; i < 4; ++i) ridx[i] = erow[e0 + lq4 * 4 + i];

#pragma unroll
    for (int ct = 0; ct < 8; ++ct) {
        floatx4 acc = {0.f, 0.f, 0.f, 0.f};
        const unsigned short* wr = wt1b + (ct * 16 + lm) * NH + lq4 * 8;
#pragma unroll
        for (int ks = 0; ks < 4; ++ks) {
            bf16x8 b = load_frag(wr + ks * 32);
            acc = __builtin_amdgcn_mfma_f32_16x16x32_bf16(a2[ks], b, acc, 0, 0, 0);
        }
        const int c = ct * 16 + lm;
        const float bb = b1b[c];
#pragma unroll
        for (int i = 0; i < 4; ++i)
            atomicAdd(&sums[ridx[i] * NH + c], acc[i] + bb);
    }
}

// ---------------------------------------------------------------------------
// Node MLP: A = [x[n] | sums[n]/max(cnt,1)], same structure, direct store.
// ---------------------------------------------------------------------------
__global__ __launch_bounds__(256) void node_mlp_kernel(
    const float* __restrict__ x,
    const float* __restrict__ sums, const float* __restrict__ cnt,
    const unsigned short* __restrict__ wt2a, const float* __restrict__ b2a,
    const float* __restrict__ g2, const float* __restrict__ be2,
    const unsigned short* __restrict__ wt2b, const float* __restrict__ b2b,
    float* __restrict__ out)
{
    __shared__ unsigned short Atile[4][16][KA + 8];
    __shared__ unsigned short Ttile[4][16][NH + 8];

    const int wave = threadIdx.x >> 6;
    const int lane = threadIdx.x & 63;
    const int n0 = blockIdx.x * 64 + wave * 16;

    {
        const int lrow = lane >> 2;
        const int lq   = lane & 3;
        int n = n0 + lrow;
        if (n >= NN) n = NN - 1;
        const float inv = 1.f / fmaxf(cnt[n], 1.f);
        const float4* xr = (const float4*)(x + n * NF);
        const float4* sr = (const float4*)(sums + n * NH);
        unsigned short* Ar = &Atile[wave][lrow][0];
#pragma unroll
        for (int it = 0; it < 8; ++it) {
            int c4 = lq + it * 4;
            float4 v = xr[c4];
            uint2 w;
            w.x = (unsigned)f2bf(v.x) | ((unsigned)f2bf(v.y) << 16);
            w.y = (unsigned)f2bf(v.z) | ((unsigned)f2bf(v.w) << 16);
            *(uint2*)&Ar[c4 * 4] = w;
            float4 v2 = sr[c4];
            uint2 w2;
            w2.x = (unsigned)f2bf(v2.x * inv) | ((unsigned)f2bf(v2.y * inv) << 16);
            w2.y = (unsigned)f2bf(v2.z * inv) | ((unsigned)f2bf(v2.w * inv) << 16);
            *(uint2*)&Ar[128 + c4 * 4] = w2;
        }
    }
    __syncthreads();

    const int lm  = lane & 15;
    const int lq4 = lane >> 4;

    bf16x8 a1[8];
#pragma unroll
    for (int ks = 0; ks < 8; ++ks)
        a1[ks] = load_frag(&Atile[wave][lm][ks * 32 + lq4 * 8]);

    floatx4 acc1[8];
#pragma unroll
    for (int ct = 0; ct < 8; ++ct) {
        floatx4 acc = {0.f, 0.f, 0.f, 0.f};
        const unsigned short* wr = wt2a + (ct * 16 + lm) * KA + lq4 * 8;
#pragma unroll
        for (int ks = 0; ks < 8; ++ks) {
            bf16x8 b = load_frag(wr + ks * 32);
            acc = __builtin_amdgcn_mfma_f32_16x16x32_bf16(a1[ks], b, acc, 0, 0, 0);
        }
        acc1[ct] = acc;
    }

    float sum_[4] = {0, 0, 0, 0}, sq_[4] = {0, 0, 0, 0};
#pragma unroll
    for (int ct = 0; ct < 8; ++ct) {
        const float bb = b2a[ct * 16 + lm];
#pragma unroll
        for (int i = 0; i < 4; ++i) {
            float v = acc1[ct][i] + bb;
            v = fmaxf(v, 0.f);
            acc1[ct][i] = v;
            sum_[i] += v;
            sq_[i]  += v * v;
        }
    }
#pragma unroll
    for (int m = 1; m < 16; m <<= 1) {
#pragma unroll
        for (int i = 0; i < 4; ++i) {
            sum_[i] += __shfl_xor(sum_[i], m, 64);
            sq_[i]  += __shfl_xor(sq_[i],  m, 64);
        }
    }
    float mu[4], rs[4];
#pragma unroll
    for (int i = 0; i < 4; ++i) {
        mu[i] = sum_[i] * (1.f / NH);
        float var = sq_[i] * (1.f / NH) - mu[i] * mu[i];
        rs[i] = rsqrtf(var + LN_EPS);
    }
#pragma unroll
    for (int ct = 0; ct < 8; ++ct) {
        const int c = ct * 16 + lm;
        const float gg = g2[c], bb = be2[c];
#pragma unroll
        for (int i = 0; i < 4; ++i) {
            float nv = (acc1[ct][i] - mu[i]) * rs[i] * gg + bb;
            Ttile[wave][lq4 * 4 + i][c] = f2bf(nv);
        }
    }
    __syncthreads();

    bf16x8 a2[4];
#pragma unroll
    for (int ks = 0; ks < 4; ++ks)
        a2[ks] = load_frag(&Ttile[wave][lm][ks * 32 + lq4 * 8]);

#pragma unroll
    for (int ct = 0; ct < 8; ++ct) {
        floatx4 acc = {0.f, 0.f, 0.f, 0.f};
        const unsigned short* wr = wt2b + (ct * 16 + lm) * NH + lq4 * 8;
#pragma unroll
        for (int ks = 0; ks < 4; ++ks) {
            bf16x8 b = load_frag(wr + ks * 32);
            acc = __builtin_amdgcn_mfma_f32_16x16x32_bf16(a2[ks], b, acc, 0, 0, 0);
        }
        const int c = ct * 16 + lm;
        const float bb = b2b[c];
#pragma unroll
        for (int i = 0; i < 4; ++i) {
            int n = n0 + lq4 * 4 + i;
            if (n < NN) out[n * NT + c] = acc[i] + bb;
        }
    }
}

// ---------------------------------------------------------------------------
// Workspace layout (bytes):
//   [0,            5,120,000)  sums   f32 [10000][128]
//   [5,120,000,    5,160,000)  cnt    f32 [10000]
//   [5,160,000,    5,225,536)  wt1a   bf16 [128][256]
//   [5,225,536,    5,258,304)  wt1b   bf16 [128][128]
//   [5,258,304,    5,323,840)  wt2a   bf16 [128][256]
//   [5,323,840,    5,356,608)  wt2b   bf16 [128][128]
// ---------------------------------------------------------------------------
extern "C" void kernel_launch(void* const* d_in, const int* in_sizes, int n_in,
                              void* d_out, int out_size, void* d_ws, size_t ws_size,
                              hipStream_t stream) {
    const float* x     = (const float*)d_in[0];
    const int*   eidx  = (const int*)d_in[1];
    const float* eattr = (const float*)d_in[2];
    const float* W1a = (const float*)d_in[3];
    const float* b1a = (const float*)d_in[4];
    const float* g1  = (const float*)d_in[5];
    const float* be1 = (const float*)d_in[6];
    const float* W1b = (const float*)d_in[7];
    const float* b1b = (const float*)d_in[8];
    const float* W2a = (const float*)d_in[9];
    const float* b2a = (const float*)d_in[10];
    const float* g2  = (const float*)d_in[11];
    const float* be2 = (const float*)d_in[12];
    const float* W2b = (const float*)d_in[13];
    const float* b2b = (const float*)d_in[14];

    char* ws = (char*)d_ws;
    float* sums = (float*)ws;
    float* cnt  = (float*)(ws + 5120000);
    unsigned short* wt1a = (unsigned short*)(ws + 5160000);
    unsigned short* wt1b = (unsigned short*)(ws + 5225536);
    unsigned short* wt2a = (unsigned short*)(ws + 5258304);
    unsigned short* wt2b = (unsigned short*)(ws + 5323840);

    hipMemsetAsync(ws, 0, 5160000, stream);   // zero sums + cnt
    conv_weights<<<384, 256, 0, stream>>>(W1a, W1b, W2a, W2b, wt1a, wt1b, wt2a, wt2b);
    count_edges<<<(NE + 255) / 256, 256, 0, stream>>>(eidx, cnt);
    edge_mlp_kernel<<<NE / 64, 256, 0, stream>>>(x, eidx, eidx + NE, eattr,
                                                 wt1a, b1a, g1, be1, wt1b, b1b, sums);
    node_mlp_kernel<<<(NN + 63) / 64, 256, 0, stream>>>(x, sums, cnt,
                                                        wt2a, b2a, g2, be2, wt2b, b2b,
                                                        (float*)d_out);
}